// Round 1
// baseline (526.673 us; speedup 1.0000x reference)
//
#include <hip/hip_runtime.h>
#include <hip/hip_bf16.h>
#include <math.h>

#define D_MODEL 4096
#define D_FF    11008
#define F4      (D_FF / 4)     // 2752 float4 columns in Wgatet rows
#define D4      (D_MODEL / 4)  // 1024 float4 columns in Wup/Wdownt rows

// ---------------------------------------------------------------------------
// Zero-init: raw-gate accumulator (ws) and the output (atomicAdd targets).
// Done with a kernel (not hipMemsetAsync) to be 100% graph-capture safe.
// ---------------------------------------------------------------------------
__global__ __launch_bounds__(256) void zero_init_k(float* __restrict__ a, int na,
                                                   float* __restrict__ b, int nb) {
    int i = blockIdx.x * 256 + threadIdx.x;
    int n = na + nb;
    for (; i < n; i += gridDim.x * 256) {
        if (i < na) a[i] = 0.0f;
        else        b[i - na] = 0.0f;
    }
}

// ---------------------------------------------------------------------------
// Kernel 1: raw[j] += sum_{i in chunk} x[i] * Wgatet[i][j]
// Rank-1-update decomposition: each thread owns 4 consecutive columns (one
// float4), each block owns a 32-row chunk. Coalesced float4 reads of Wgatet.
// fp32 atomicAdd partials (128 adders per column — low contention).
// ---------------------------------------------------------------------------
#define K1_ROWS 32
__global__ __launch_bounds__(256) void gate_gemv_k(const float* __restrict__ x,
                                                   const float* __restrict__ Wg,
                                                   float* __restrict__ raw) {
    const int j4  = blockIdx.x * 256 + threadIdx.x;   // float4 column index
    const bool act = (j4 < F4);
    const int i0  = blockIdx.y * K1_ROWS;
    const float4* __restrict__ W4 = (const float4*)Wg;

    float4 acc = make_float4(0.f, 0.f, 0.f, 0.f);
    for (int i = i0; i < i0 + K1_ROWS; i += 4) {
        const float4 xv = *(const float4*)(x + i);    // wave-uniform scalar load
        if (act) {
            float4 w;
            w = W4[(size_t)(i + 0) * F4 + j4];
            acc.x += xv.x * w.x; acc.y += xv.x * w.y; acc.z += xv.x * w.z; acc.w += xv.x * w.w;
            w = W4[(size_t)(i + 1) * F4 + j4];
            acc.x += xv.y * w.x; acc.y += xv.y * w.y; acc.z += xv.y * w.z; acc.w += xv.y * w.w;
            w = W4[(size_t)(i + 2) * F4 + j4];
            acc.x += xv.z * w.x; acc.y += xv.z * w.y; acc.z += xv.z * w.z; acc.w += xv.z * w.w;
            w = W4[(size_t)(i + 3) * F4 + j4];
            acc.x += xv.w * w.x; acc.y += xv.w * w.y; acc.z += xv.w * w.z; acc.w += xv.w * w.w;
        }
    }
    if (act) {
        float* p = raw + 4 * j4;
        atomicAdd(p + 0, acc.x);
        atomicAdd(p + 1, acc.y);
        atomicAdd(p + 2, acc.z);
        atomicAdd(p + 3, acc.w);
    }
}

// ---------------------------------------------------------------------------
// Kernel 2: x1 = silu(raw[j]); if |x1| > thr: z[j] = dot(x, Wup[j,:]) * x1
// One 64-lane wave per d_ff row. Whole wave early-outs on unflagged rows,
// skipping the 16 KB Wup row read (the CATS sparsity win).
// ---------------------------------------------------------------------------
__global__ __launch_bounds__(256) void up_gemv_k(const float* __restrict__ x,
                                                 const float* __restrict__ Wup,
                                                 const float* __restrict__ raw,
                                                 const float* __restrict__ thr_p,
                                                 float* __restrict__ z) {
    const int wave = threadIdx.x >> 6;
    const int lane = threadIdx.x & 63;
    const int j = blockIdx.x * 4 + wave;   // D_FF = 2752 blocks * 4 waves exactly

    const float r  = raw[j];
    const float x1 = r / (1.0f + __expf(-r));   // silu
    const float thr = *thr_p;

    if (!(fabsf(x1) > thr)) {
        if (lane == 0) z[j] = 0.0f;
        return;
    }

    const float4* __restrict__ A = (const float4*)(Wup + (size_t)j * D_MODEL);
    const float4* __restrict__ X = (const float4*)x;
    float acc = 0.0f;
#pragma unroll
    for (int k = 0; k < 16; ++k) {
        const float4 a  = A[k * 64 + lane];
        const float4 xv = X[k * 64 + lane];
        acc += a.x * xv.x + a.y * xv.y + a.z * xv.z + a.w * xv.w;
    }
#pragma unroll
    for (int off = 32; off > 0; off >>= 1)
        acc += __shfl_down(acc, off);

    if (lane == 0) z[j] = acc * x1;
}

// ---------------------------------------------------------------------------
// Kernel 3: out[i] += sum_{j in chunk} z[j] * Wdownt[j][i]
// Each block owns 16 d_ff rows; 256 threads cover all 4096 output columns
// with 4 float4 accumulators each. Wave-uniform skip of z[j]==0 rows.
// ---------------------------------------------------------------------------
#define K3_ROWS 16
__global__ __launch_bounds__(256) void down_acc_k(const float* __restrict__ z,
                                                  const float* __restrict__ Wd,
                                                  float* __restrict__ out) {
    const int t  = threadIdx.x;
    const int j0 = blockIdx.x * K3_ROWS;
    const float4* __restrict__ W4 = (const float4*)Wd;

    float4 acc[4];
#pragma unroll
    for (int s = 0; s < 4; ++s) acc[s] = make_float4(0.f, 0.f, 0.f, 0.f);

    for (int r = 0; r < K3_ROWS; ++r) {
        const int j = j0 + r;
        const float zj = z[j];                 // wave-uniform scalar load
        if (zj != 0.0f) {
#pragma unroll
            for (int s = 0; s < 4; ++s) {
                const float4 w = W4[(size_t)j * D4 + s * 256 + t];
                acc[s].x += zj * w.x;
                acc[s].y += zj * w.y;
                acc[s].z += zj * w.z;
                acc[s].w += zj * w.w;
            }
        }
    }
#pragma unroll
    for (int s = 0; s < 4; ++s) {
        float* p = out + (s * 256 + t) * 4;
        atomicAdd(p + 0, acc[s].x);
        atomicAdd(p + 1, acc[s].y);
        atomicAdd(p + 2, acc[s].z);
        atomicAdd(p + 3, acc[s].w);
    }
}

// ---------------------------------------------------------------------------
extern "C" void kernel_launch(void* const* d_in, const int* in_sizes, int n_in,
                              void* d_out, int out_size, void* d_ws, size_t ws_size,
                              hipStream_t stream) {
    const float* x    = (const float*)d_in[0];   // [1,1,4096]
    const float* Wup  = (const float*)d_in[1];   // [11008, 4096]
    const float* Wg   = (const float*)d_in[2];   // [4096, 11008]
    const float* Wd   = (const float*)d_in[3];   // [11008, 4096]
    const float* thr  = (const float*)d_in[4];   // scalar
    float* out = (float*)d_out;                  // [1,1,4096]

    float* raw = (float*)d_ws;                   // [11008] raw gate dots
    float* z   = raw + D_FF;                     // [11008] gated ups

    // zero the atomicAdd targets (ws and d_out are poisoned with 0xAA)
    zero_init_k<<<59, 256, 0, stream>>>(raw, D_FF, out, D_MODEL);

    // 1) raw = x @ Wgatet   (11 column-tiles x 128 row-chunks = 1408 blocks)
    gate_gemv_k<<<dim3(11, D_MODEL / K1_ROWS), 256, 0, stream>>>(x, Wg, raw);

    // 2) z = flag ? (x @ Wup^T) * silu(raw) : 0   (one wave per row)
    up_gemv_k<<<D_FF / 4, 256, 0, stream>>>(x, Wup, raw, thr, z);

    // 3) out = z @ Wdownt   (688 blocks x 16 rows)
    down_acc_k<<<D_FF / K3_ROWS, 256, 0, stream>>>(z, Wd, out);
}

// Round 2
// 469.150 us; speedup vs baseline: 1.1226x; 1.1226x over previous
//
#include <hip/hip_runtime.h>
#include <hip/hip_bf16.h>
#include <math.h>

#define D_MODEL 4096
#define D_FF    11008
#define F4      (D_FF / 4)       // 2752 float4 columns in Wgatet rows
#define D4      (D_MODEL / 4)    // 1024 float4 columns in Wup/Wdownt rows

#define K1_ROWS   32
#define K1_CHUNKS (D_MODEL / K1_ROWS)   // 128 partial rows for the gate GEMV
#define K3_BLOCKS 256
#define K3_ROWS   (D_FF / K3_BLOCKS)    // 43 d_ff rows per down-block

// ---------------------------------------------------------------------------
// Kernel 1: gate partials.  gpart[c][j] = sum_{i in chunk c} x[i]*Wgatet[i][j]
// Rank-1-update decomposition; each thread owns one float4 of columns, each
// block one 32-row chunk. Coalesced 1KB/instr reads, coalesced float4 stores,
// NO atomics, NO zero-init needed.
// ---------------------------------------------------------------------------
__global__ __launch_bounds__(256) void gate_part_k(const float* __restrict__ x,
                                                   const float* __restrict__ Wg,
                                                   float* __restrict__ gpart) {
    const int j4  = blockIdx.x * 256 + threadIdx.x;   // float4 column index
    const bool act = (j4 < F4);
    const int i0  = blockIdx.y * K1_ROWS;
    const float4* __restrict__ W4 = (const float4*)Wg;

    float4 acc = make_float4(0.f, 0.f, 0.f, 0.f);
    for (int i = i0; i < i0 + K1_ROWS; i += 4) {
        const float4 xv = *(const float4*)(x + i);    // wave-uniform load
        if (act) {
            float4 w;
            w = W4[(size_t)(i + 0) * F4 + j4];
            acc.x += xv.x * w.x; acc.y += xv.x * w.y; acc.z += xv.x * w.z; acc.w += xv.x * w.w;
            w = W4[(size_t)(i + 1) * F4 + j4];
            acc.x += xv.y * w.x; acc.y += xv.y * w.y; acc.z += xv.y * w.z; acc.w += xv.y * w.w;
            w = W4[(size_t)(i + 2) * F4 + j4];
            acc.x += xv.z * w.x; acc.y += xv.z * w.y; acc.z += xv.z * w.z; acc.w += xv.z * w.w;
            w = W4[(size_t)(i + 3) * F4 + j4];
            acc.x += xv.w * w.x; acc.y += xv.w * w.y; acc.z += xv.w * w.z; acc.w += xv.w * w.w;
        }
    }
    if (act)
        *(float4*)(gpart + (size_t)blockIdx.y * D_FF + 4 * (size_t)j4) = acc;
}

// ---------------------------------------------------------------------------
// Kernel 2: reduce gate partials -> raw; x1 = silu(raw); if |x1| > thr:
// z[j] = dot(x, Wup[j,:]) * x1, else 0.  One 64-lane wave per d_ff row;
// whole wave early-outs on unflagged rows (skips the 16 KB Wup row read).
// ---------------------------------------------------------------------------
__global__ __launch_bounds__(256) void up_gemv_k(const float* __restrict__ x,
                                                 const float* __restrict__ Wup,
                                                 const float* __restrict__ gpart,
                                                 const float* __restrict__ thr_p,
                                                 float* __restrict__ z) {
    const int wave = threadIdx.x >> 6;
    const int lane = threadIdx.x & 63;
    const int j = blockIdx.x * 4 + wave;   // D_FF = 2752 blocks * 4 waves

    // butterfly-reduce the 128 gate partials for row j (L2-resident, 5.6 MB)
    float r = gpart[(size_t)lane * D_FF + j] + gpart[(size_t)(lane + 64) * D_FF + j];
#pragma unroll
    for (int off = 32; off > 0; off >>= 1)
        r += __shfl_xor(r, off);
    // every lane now holds raw[j]

    const float x1  = r / (1.0f + __expf(-r));   // silu
    const float thr = *thr_p;

    if (!(fabsf(x1) > thr)) {
        if (lane == 0) z[j] = 0.0f;
        return;
    }

    const float4* __restrict__ A = (const float4*)(Wup + (size_t)j * D_MODEL);
    const float4* __restrict__ X = (const float4*)x;
    float acc = 0.0f;
#pragma unroll
    for (int k = 0; k < 16; ++k) {
        const float4 a  = A[k * 64 + lane];
        const float4 xv = X[k * 64 + lane];
        acc += a.x * xv.x + a.y * xv.y + a.z * xv.z + a.w * xv.w;
    }
#pragma unroll
    for (int off = 32; off > 0; off >>= 1)
        acc += __shfl_down(acc, off);

    if (lane == 0) z[j] = acc * x1;
}

// ---------------------------------------------------------------------------
// Kernel 3: down partials. Block b accumulates rows [b*43, b*43+43) of
// z[j]*Wdownt[j,:] into 8 registers/thread (512 thr cover 4096 cols), then
// writes one coalesced 16 KB partial. Wave-uniform skip of z[j]==0 rows.
// 256 blocks = exactly 1 per CU, perfectly balanced. NO atomics.
// ---------------------------------------------------------------------------
__global__ __launch_bounds__(512) void down_part_k(const float* __restrict__ z,
                                                   const float* __restrict__ Wd,
                                                   float* __restrict__ dpart) {
    const int t  = threadIdx.x;          // 0..511
    const int j0 = blockIdx.x * K3_ROWS;
    const float4* __restrict__ W4 = (const float4*)Wd;

    float4 a0 = make_float4(0.f, 0.f, 0.f, 0.f);
    float4 a1 = make_float4(0.f, 0.f, 0.f, 0.f);

    for (int r = 0; r < K3_ROWS; ++r) {
        const int j = j0 + r;
        const float zj = z[j];           // wave-uniform load
        if (zj != 0.0f) {
            const float4 w0 = W4[(size_t)j * D4 + t];
            const float4 w1 = W4[(size_t)j * D4 + 512 + t];
            a0.x += zj * w0.x; a0.y += zj * w0.y; a0.z += zj * w0.z; a0.w += zj * w0.w;
            a1.x += zj * w1.x; a1.y += zj * w1.y; a1.z += zj * w1.z; a1.w += zj * w1.w;
        }
    }
    float4* dp = (float4*)dpart + (size_t)blockIdx.x * D4;
    dp[t]       = a0;
    dp[512 + t] = a1;
}

// ---------------------------------------------------------------------------
// Kernel 4: out[i] = sum_{b=0..255} dpart[b][i].  4 MB, L2-resident.
// 32 blocks; block g owns 32 float4 columns; 8 b-slices reduced via LDS.
// Writes every output exactly once (d_out is poisoned each launch).
// ---------------------------------------------------------------------------
__global__ __launch_bounds__(256) void down_reduce_k(const float* __restrict__ dpart,
                                                     float* __restrict__ out) {
    const int t     = threadIdx.x;
    const int col   = (t & 31);          // 0..31 within this block's column tile
    const int slice = (t >> 5);          // 0..7, each covers 32 b's
    const int c4    = blockIdx.x * 32 + col;   // global float4 column

    const float4* __restrict__ dp = (const float4*)dpart;
    float4 acc = make_float4(0.f, 0.f, 0.f, 0.f);
    for (int s = 0; s < 32; ++s) {
        const int b = slice * 32 + s;
        const float4 v = dp[(size_t)b * D4 + c4];
        acc.x += v.x; acc.y += v.y; acc.z += v.z; acc.w += v.w;
    }

    __shared__ float4 red[256];
    red[t] = acc;
    __syncthreads();
    if (t < 32) {
        float4 r = red[t];
#pragma unroll
        for (int s = 1; s < 8; ++s) {
            const float4 v = red[t + 32 * s];
            r.x += v.x; r.y += v.y; r.z += v.z; r.w += v.w;
        }
        ((float4*)out)[c4] = r;
    }
}

// ---------------------------------------------------------------------------
extern "C" void kernel_launch(void* const* d_in, const int* in_sizes, int n_in,
                              void* d_out, int out_size, void* d_ws, size_t ws_size,
                              hipStream_t stream) {
    const float* x    = (const float*)d_in[0];   // [1,1,4096]
    const float* Wup  = (const float*)d_in[1];   // [11008, 4096]
    const float* Wg   = (const float*)d_in[2];   // [4096, 11008]
    const float* Wd   = (const float*)d_in[3];   // [11008, 4096]
    const float* thr  = (const float*)d_in[4];   // scalar
    float* out = (float*)d_out;                  // [1,1,4096]

    float* gpart = (float*)d_ws;                         // 128 * 11008 floats (5.6 MB)
    float* z     = gpart + (size_t)K1_CHUNKS * D_FF;     // 11008 floats
    float* dpart = z + D_FF;                             // 256 * 4096 floats (4 MB)

    // 1) gate partials: 11 column-tiles x 128 row-chunks
    gate_part_k<<<dim3(11, K1_CHUNKS), 256, 0, stream>>>(x, Wg, gpart);

    // 2) z = flag ? (x @ Wup^T) * silu(raw) : 0
    up_gemv_k<<<D_FF / 4, 256, 0, stream>>>(x, Wup, gpart, thr, z);

    // 3) down partials: 256 blocks x 43 rows
    down_part_k<<<K3_BLOCKS, 512, 0, stream>>>(z, Wd, dpart);

    // 4) out = column-sum of partials
    down_reduce_k<<<D4 / 32, 256, 0, stream>>>(dpart, out);
}